// Round 1
// baseline (740.192 us; speedup 1.0000x reference)
//
#include <hip/hip_runtime.h>

#define NB   16384
#define LSEQ 50
#define D    100
#define KP   100
#define FF   2048
#define CH   128
#define NCH  (FF/CH)
#define ROWS 32
#define EPSV 1e-5f
#define SWB  136      // LDS u16 stride for MFMA tiles (68 dwords -> conflict-optimal)

typedef unsigned short u16;
typedef unsigned int   u32;
typedef __attribute__((ext_vector_type(8))) short bf16x8;
typedef __attribute__((ext_vector_type(4))) float f32x4;

// d_ws layout: [0, NB*D) fp32 xws ; 128 fp32 bcomb ; then u16 region:
#define WCP_OFF  0          // Wcomb = Wo@Wv padded [112][128]
#define W1P_OFF  14336      // [2048][128]
#define W2P_OFF  276480     // [112][2048]
#define RECP_OFF 505856     // rec padded [112][128]
#define PREP_N   520192

__device__ __forceinline__ float bflo(u32 u){ return __uint_as_float(u << 16); }
__device__ __forceinline__ float bfhi(u32 u){ return __uint_as_float(u & 0xffff0000u); }
__device__ __forceinline__ u16 f2bf(float f){
    u32 b = __float_as_uint(f);
    b += 0x7fffu + ((b >> 16) & 1u);   // RNE
    return (u16)(b >> 16);
}

// ---------------- Kernel 0: weight prep -> padded bf16 layouts ---------------
// Also folds attention: Wcomb = Wo @ Wv, bcomb = Wo @ bv + bo (fp32 accum).
__global__ __launch_bounds__(256) void k_prep(
    const float* __restrict__ ipw, const float* __restrict__ opw,
    const float* __restrict__ ipb, const float* __restrict__ opb,
    const float* __restrict__ w1,  const float* __restrict__ w2,
    const float* __restrict__ rec, u16* __restrict__ dst,
    float* __restrict__ bcomb)
{
    int i = blockIdx.x * 256 + threadIdx.x;
    if (i >= PREP_N + 128) return;
    if (i < W1P_OFF) {                       // Wcomb padded [112][128]
        int n = i >> 7, k = i & 127;
        float a = 0.f;
        if (n < D && k < D) {
            // Wcomb[n][k] = sum_j Wo[n][j] * Wv[j][k]; Wv = ipw rows 2D..3D-1
            for (int j = 0; j < D; ++j)
                a += opw[n * D + j] * ipw[(2 * D + j) * D + k];
        }
        dst[i] = f2bf(a);
    } else if (i < W2P_OFF) {                // W1 padded [2048][128]
        int j = i - W1P_OFF; int r = j >> 7, k = j & 127;
        dst[i] = (k < D) ? f2bf(w1[r * D + k]) : (u16)0;
    } else if (i < RECP_OFF) {               // W2 padded [112][2048]
        int j = i - W2P_OFF; int c = j >> 11, jj = j & 2047;
        dst[i] = (c < D) ? f2bf(w2[c * FF + jj]) : (u16)0;
    } else if (i < PREP_N) {                 // rec padded [112][128]
        int j = i - RECP_OFF; int n = j >> 7, k = j & 127;
        dst[i] = (n < D && k < D) ? f2bf(rec[n * D + k]) : (u16)0;
    } else {                                 // bcomb (fp32)
        int n = i - PREP_N;
        float a = 0.f;
        if (n < D) {
            a = opb[n];
            for (int j = 0; j < D; ++j)
                a += opw[n * D + j] * ipb[2 * D + j];
        }
        bcomb[n] = a;
    }
}

// ---------------- Kernel 1: x = sum_l item_emb[item_seq[b,l]]  (fp32) --------
__global__ __launch_bounds__(256) void k_gather(const int* __restrict__ seq,
        const float* __restrict__ emb, float* __restrict__ xout)
{
    __shared__ float2 part[5][50];
    const int row = blockIdx.x;
    const int t   = threadIdx.x;
    const int c2  = t % 50;          // float2 column
    const int lg  = t / 50;          // 0..5 (group 5 idle)
    float ax = 0.f, ay = 0.f;
    if (lg < 5) {
        const float2* e2 = (const float2*)emb;
        #pragma unroll
        for (int u = 0; u < 10; ++u) {
            int idx = seq[row * LSEQ + lg * 10 + u];
            float2 w = e2[(size_t)idx * 50 + c2];
            ax += w.x; ay += w.y;
        }
        float2 p; p.x = ax; p.y = ay;
        part[lg][c2] = p;
    }
    __syncthreads();
    if (t < 50) {
        float sx = 0.f, sy = 0.f;
        #pragma unroll
        for (int g = 0; g < 5; ++g) { sx += part[g][t].x; sy += part[g][t].y; }
        float2 v; v.x = sx; v.y = sy;
        ((float2*)xout)[(size_t)row * 50 + t] = v;
    }
}

// ---------------- Kernel 2: fused transformer block + scoring (MFMA) ---------
__device__ __forceinline__ void gemm2x2(
    const u16* __restrict__ Alds, const u16* __restrict__ Blds,
    int n0, int nvalid, int fl, int fq, f32x4 acc[2][2])
{
    #pragma unroll
    for (int ks = 0; ks < 4; ++ks) {
        const int kb = ks * 32 + fq * 8;
        bf16x8 a0 = *(const bf16x8*)(Alds + fl * SWB + kb);
        bf16x8 a1 = *(const bf16x8*)(Alds + (16 + fl) * SWB + kb);
        bf16x8 b0 = *(const bf16x8*)(Blds + (n0 + fl) * SWB + kb);
        acc[0][0] = __builtin_amdgcn_mfma_f32_16x16x32_bf16(a0, b0, acc[0][0], 0, 0, 0);
        acc[1][0] = __builtin_amdgcn_mfma_f32_16x16x32_bf16(a1, b0, acc[1][0], 0, 0, 0);
        if (nvalid > 1) {
            bf16x8 b1 = *(const bf16x8*)(Blds + (n0 + 16 + fl) * SWB + kb);
            acc[0][1] = __builtin_amdgcn_mfma_f32_16x16x32_bf16(a0, b1, acc[0][1], 0, 0, 0);
            acc[1][1] = __builtin_amdgcn_mfma_f32_16x16x32_bf16(a1, b1, acc[1][1], 0, 0, 0);
        }
    }
}

template<bool TOBF>
__device__ __forceinline__ void ln_tile(float* __restrict__ A, u16* __restrict__ dstbf,
        const float* __restrict__ g, const float* __restrict__ b, int tid)
{
    const int r  = tid >> 3;
    const int s8 = tid & 7;
    float sum = 0.f, sq = 0.f;
    for (int k = s8; k < D; k += 8) {
        float v = A[r * 104 + k];
        sum += v; sq += v * v;
    }
    sum += __shfl_xor(sum, 1, 64); sq += __shfl_xor(sq, 1, 64);
    sum += __shfl_xor(sum, 2, 64); sq += __shfl_xor(sq, 2, 64);
    sum += __shfl_xor(sum, 4, 64); sq += __shfl_xor(sq, 4, 64);
    float m   = sum * 0.01f;
    float var = sq * 0.01f - m * m;
    float rs  = rsqrtf(var + EPSV);
    for (int k = s8; k < D; k += 8) {
        float v = A[r * 104 + k];
        float y = (v - m) * rs * g[k] + b[k];
        A[r * 104 + k] = y;
        if (TOBF) dstbf[r * SWB + k] = f2bf(y);
    }
}

__global__ __launch_bounds__(256) void k_fused(
    const float* __restrict__ xin,
    const int*  __restrict__ ipred,
    const u16*  __restrict__ wbase,        // prep region
    const float* __restrict__ rec_b,
    const float* __restrict__ bcomb,
    const float* __restrict__ ln1g, const float* __restrict__ ln1b,
    const float* __restrict__ ln2g, const float* __restrict__ ln2b,
    const float* __restrict__ b1, const float* __restrict__ b2,
    float* __restrict__ out)
{
    __shared__ __align__(16) float A0[ROWS * 104];     // x -> x+attn -> h -> h+f2 -> scores
    __shared__ __align__(16) u16   Abf[ROWS * SWB];    // x -> h -> s (bf16, A-operand)
    __shared__ __align__(16) u16   Hbf[ROWS * SWB];    // H chunk (bf16, A-operand)
    __shared__ __align__(16) u16   Wbuf[128 * SWB];    // B-operand weight tile / rec
    __shared__ float sRB[112];                         // rec_b[0..99]

    const int tid  = threadIdx.x;
    const int wv   = tid >> 6;
    const int lane = tid & 63;
    const int fl   = lane & 15;
    const int fq   = lane >> 4;
    const int row0 = blockIdx.x * ROWS;
    const int n0   = wv * 32;
    const int nv7  = (wv < 3) ? 2 : 1;    // 7 N-tiles over 4 waves

    const u16* Wcp = wbase + WCP_OFF;
    const u16* W1p = wbase + W1P_OFF;
    const u16* W2p = wbase + W2P_OFF;
    const u16* recp= wbase + RECP_OFF;

    // stage x (fp32 + bf16 padded), Wcomb tile, rec_b head
    for (int i = tid; i < ROWS * 128; i += 256) {
        int r = i >> 7, k = i & 127;
        float v = (k < D) ? xin[(size_t)(row0 + r) * D + k] : 0.f;
        if (k < D) A0[r * 104 + k] = v;
        Abf[r * SWB + k] = f2bf(v);
    }
    for (int i = tid; i < 112 * 16; i += 256) {
        int r = i >> 4, cb = (i & 15) * 8;
        *(uint4*)(Wbuf + r * SWB + cb) = *(const uint4*)(Wcp + r * 128 + cb);
    }
    if (tid < D) sRB[tid] = rec_b[tid];
    __syncthreads();

    // ---- attn = x @ Wcomb^T + bcomb ; A0 += attn (V,O folded) ----
    {
        f32x4 acc[2][2] = {};
        gemm2x2(Abf, Wbuf, n0, nv7, fl, fq, acc);
        for (int t = 0; t < nv7; ++t) {
            int c = n0 + t * 16 + fl;
            if (c < D) {
                float bc = bcomb[c];
                #pragma unroll
                for (int r = 0; r < 4; ++r) {
                    int m = fq * 4 + r;
                    A0[m * 104 + c]        += acc[0][t][r] + bc;
                    A0[(16 + m) * 104 + c] += acc[1][t][r] + bc;
                }
            }
        }
        __syncthreads();      // A0 writes visible; Abf/Wbuf reads done
    }

    // ---- LN1: h = LN(x+attn) -> A0 (fp32) + Abf (bf16) ----
    ln_tile<true>(A0, Abf, ln1g, ln1b, tid);

    // ---- FFN: 16 chunks of 128 hidden, reg-prefetched weights (T14) ----
    uint4 w1r[8], w2r[7];
    #pragma unroll
    for (int j = 0; j < 8; ++j) {          // prologue: W1 chunk 0 -> regs
        int idx = j * 256 + tid;
        int r = idx >> 4, cb = (idx & 15) * 8;
        w1r[j] = *(const uint4*)(W1p + r * 128 + cb);
    }
    f32x4 facc[2][2] = {};
    for (int ch = 0; ch < NCH; ++ch) {
        __syncthreads();                   // Wbuf free (prev gemm2 / attn reads done; LN1 visible)
        #pragma unroll
        for (int j = 0; j < 8; ++j) {      // W1 regs -> LDS
            int idx = j * 256 + tid;
            int r = idx >> 4, cb = (idx & 15) * 8;
            *(uint4*)(Wbuf + r * SWB + cb) = w1r[j];
        }
        #pragma unroll
        for (int j = 0; j < 7; ++j) {      // issue W2 chunk loads early
            int idx = j * 256 + tid;
            int r = idx >> 4, cb = (idx & 15) * 8;
            w2r[j] = *(const uint4*)(W2p + ch * CH + (size_t)r * FF + cb);
        }
        __syncthreads();
        // GEMM1: H = relu(h @ W1c^T + b1c)
        f32x4 hacc[2][2] = {};
        gemm2x2(Abf, Wbuf, n0, 2, fl, fq, hacc);
        if (ch < NCH - 1) {                // issue next W1 chunk loads under MFMA
            const u16* src = W1p + (size_t)(ch + 1) * CH * 128;
            #pragma unroll
            for (int j = 0; j < 8; ++j) {
                int idx = j * 256 + tid;
                int r = idx >> 4, cb = (idx & 15) * 8;
                w1r[j] = *(const uint4*)(src + r * 128 + cb);
            }
        }
        __syncthreads();                   // gemm1's Wbuf reads done
        #pragma unroll
        for (int j = 0; j < 7; ++j) {      // W2 regs -> LDS
            int idx = j * 256 + tid;
            int r = idx >> 4, cb = (idx & 15) * 8;
            *(uint4*)(Wbuf + r * SWB + cb) = w2r[j];
        }
        #pragma unroll
        for (int t = 0; t < 2; ++t) {      // H -> bf16 LDS
            int c = n0 + t * 16 + fl;
            float b1c = b1[ch * CH + c];
            #pragma unroll
            for (int r = 0; r < 4; ++r) {
                int m = fq * 4 + r;
                Hbf[m * SWB + c]        = f2bf(fmaxf(hacc[0][t][r] + b1c, 0.f));
                Hbf[(16 + m) * SWB + c] = f2bf(fmaxf(hacc[1][t][r] + b1c, 0.f));
            }
        }
        __syncthreads();
        // GEMM2: facc += H @ W2c^T
        gemm2x2(Hbf, Wbuf, n0, nv7, fl, fq, facc);
    }

    // ---- A0 = h + f2 + b2 ----
    for (int t = 0; t < nv7; ++t) {
        int c = n0 + t * 16 + fl;
        if (c < D) {
            float b2c = b2[c];
            #pragma unroll
            for (int r = 0; r < 4; ++r) {
                int m = fq * 4 + r;
                A0[m * 104 + c]        += facc[0][t][r] + b2c;
                A0[(16 + m) * 104 + c] += facc[1][t][r] + b2c;
            }
        }
    }
    __syncthreads();          // A0 visible; last gemm2's Wbuf/Hbf reads done

    // ---- LN2 -> s (bf16 into Abf); stage rec_emb tile into Wbuf ----
    ln_tile<true>(A0, Abf, ln2g, ln2b, tid);
    for (int i = tid; i < 112 * 16; i += 256) {
        int r = i >> 4, cb = (i & 15) * 8;
        *(uint4*)(Wbuf + r * SWB + cb) = *(const uint4*)(recp + r * 128 + cb);
    }
    __syncthreads();

    // ---- scoring: scores[b, n] = dot(s[b], rec[n]) via MFMA (all n < 100) ----
    {
        f32x4 acc[2][2] = {};
        gemm2x2(Abf, Wbuf, n0, nv7, fl, fq, acc);
        for (int t = 0; t < nv7; ++t) {
            int c = n0 + t * 16 + fl;
            if (c < D) {
                #pragma unroll
                for (int r = 0; r < 4; ++r) {
                    int m = fq * 4 + r;
                    A0[m * 104 + c]        = acc[0][t][r];
                    A0[(16 + m) * 104 + c] = acc[1][t][r];
                }
            }
        }
        __syncthreads();
    }

    // ---- out[b,k] = rec_b[idx] + scores[b, idx] ----
    for (int o = tid; o < ROWS * KP; o += 256) {
        int r = o / KP, k = o - r * KP;
        int grow = row0 + r;
        int idx  = ipred[(size_t)grow * KP + k];
        out[(size_t)grow * KP + k] = sRB[idx] + A0[r * 104 + idx];
    }
}

extern "C" void kernel_launch(void* const* d_in, const int* in_sizes, int n_in,
                              void* d_out, int out_size, void* d_ws, size_t ws_size,
                              hipStream_t stream)
{
    const int*   item_seq   = (const int*)d_in[0];
    const int*   ipred      = (const int*)d_in[1];
    const float* item_emb   = (const float*)d_in[2];
    const float* rec_emb    = (const float*)d_in[3];
    const float* rec_b      = (const float*)d_in[4];
    const float* in_proj_w  = (const float*)d_in[5];
    const float* in_proj_b  = (const float*)d_in[6];
    const float* out_proj_w = (const float*)d_in[7];
    const float* out_proj_b = (const float*)d_in[8];
    const float* ln1g = (const float*)d_in[9];
    const float* ln1b = (const float*)d_in[10];
    const float* ln2g = (const float*)d_in[11];
    const float* ln2b = (const float*)d_in[12];
    const float* w1   = (const float*)d_in[13];
    const float* b1   = (const float*)d_in[14];
    const float* w2   = (const float*)d_in[15];
    const float* b2   = (const float*)d_in[16];

    float* xws    = (float*)d_ws;
    float* bcombf = xws + (size_t)NB * D;
    u16*   wbase  = (u16*)(bcombf + 128);

    k_prep<<<(PREP_N + 128 + 255) / 256, 256, 0, stream>>>(
        in_proj_w, out_proj_w, in_proj_b, out_proj_b, w1, w2, rec_emb, wbase, bcombf);
    k_gather<<<NB, 256, 0, stream>>>(item_seq, item_emb, xws);
    k_fused<<<NB / ROWS, 256, 0, stream>>>(xws, ipred, wbase, rec_b, bcombf,
        ln1g, ln1b, ln2g, ln2b, b1, b2, (float*)d_out);
}

// Round 2
// 671.062 us; speedup vs baseline: 1.1030x; 1.1030x over previous
//
#include <hip/hip_runtime.h>

#define NB   16384
#define LSEQ 50
#define D    100
#define KP   100
#define FF   2048
#define CH   128
#define NCH  (FF/CH)
#define ROWS 32
#define EPSV 1e-5f
#define SWB  136      // LDS u16 stride for MFMA tiles (68 dwords -> conflict-optimal)

typedef unsigned short u16;
typedef unsigned int   u32;
typedef __attribute__((ext_vector_type(8))) short bf16x8;
typedef __attribute__((ext_vector_type(4))) float f32x4;

// d_ws layout: [0, NB*D) fp32 xws ; 128 fp32 bcomb ; then u16 region:
#define WCP_OFF  0          // Wcomb = Wo@Wv padded [112][128]
#define W1P_OFF  14336      // [2048][128]
#define W2P_OFF  276480     // [112][2048]
#define RECP_OFF 505856     // rec padded [112][128]
#define PREP_N   520192

__device__ __forceinline__ float bflo(u32 u){ return __uint_as_float(u << 16); }
__device__ __forceinline__ float bfhi(u32 u){ return __uint_as_float(u & 0xffff0000u); }
__device__ __forceinline__ u16 f2bf(float f){
    u32 b = __float_as_uint(f);
    b += 0x7fffu + ((b >> 16) & 1u);   // RNE
    return (u16)(b >> 16);
}

// ---------------- Kernel 0: weight prep -> padded bf16 layouts ---------------
// Also folds attention: Wcomb = Wo @ Wv, bcomb = Wo @ bv + bo (fp32 accum).
__global__ __launch_bounds__(256) void k_prep(
    const float* __restrict__ ipw, const float* __restrict__ opw,
    const float* __restrict__ ipb, const float* __restrict__ opb,
    const float* __restrict__ w1,  const float* __restrict__ w2,
    const float* __restrict__ rec, u16* __restrict__ dst,
    float* __restrict__ bcomb)
{
    int i = blockIdx.x * 256 + threadIdx.x;
    if (i >= PREP_N + 128) return;
    if (i < W1P_OFF) {                       // Wcomb padded [112][128]
        int n = i >> 7, k = i & 127;
        float a = 0.f;
        if (n < D && k < D) {
            // Wcomb[n][k] = sum_j Wo[n][j] * Wv[j][k]; Wv = ipw rows 2D..3D-1
            for (int j = 0; j < D; ++j)
                a += opw[n * D + j] * ipw[(2 * D + j) * D + k];
        }
        dst[i] = f2bf(a);
    } else if (i < W2P_OFF) {                // W1 padded [2048][128]
        int j = i - W1P_OFF; int r = j >> 7, k = j & 127;
        dst[i] = (k < D) ? f2bf(w1[r * D + k]) : (u16)0;
    } else if (i < RECP_OFF) {               // W2 padded [112][2048]
        int j = i - W2P_OFF; int c = j >> 11, jj = j & 2047;
        dst[i] = (c < D) ? f2bf(w2[c * FF + jj]) : (u16)0;
    } else if (i < PREP_N) {                 // rec padded [112][128]
        int j = i - RECP_OFF; int n = j >> 7, k = j & 127;
        dst[i] = (n < D && k < D) ? f2bf(rec[n * D + k]) : (u16)0;
    } else {                                 // bcomb (fp32)
        int n = i - PREP_N;
        float a = 0.f;
        if (n < D) {
            a = opb[n];
            for (int j = 0; j < D; ++j)
                a += opw[n * D + j] * ipb[2 * D + j];
        }
        bcomb[n] = a;
    }
}

// ---------------- Kernel 1: x = sum_l item_emb[item_seq[b,l]]  (fp32) --------
__global__ __launch_bounds__(256) void k_gather(const int* __restrict__ seq,
        const float* __restrict__ emb, float* __restrict__ xout)
{
    __shared__ float2 part[5][50];
    const int row = blockIdx.x;
    const int t   = threadIdx.x;
    const int c2  = t % 50;          // float2 column
    const int lg  = t / 50;          // 0..5 (group 5 idle)
    float ax = 0.f, ay = 0.f;
    if (lg < 5) {
        const float2* e2 = (const float2*)emb;
        #pragma unroll
        for (int u = 0; u < 10; ++u) {
            int idx = seq[row * LSEQ + lg * 10 + u];
            float2 w = e2[(size_t)idx * 50 + c2];
            ax += w.x; ay += w.y;
        }
        float2 p; p.x = ax; p.y = ay;
        part[lg][c2] = p;
    }
    __syncthreads();
    if (t < 50) {
        float sx = 0.f, sy = 0.f;
        #pragma unroll
        for (int g = 0; g < 5; ++g) { sx += part[g][t].x; sy += part[g][t].y; }
        float2 v; v.x = sx; v.y = sy;
        ((float2*)xout)[(size_t)row * 50 + t] = v;
    }
}

// ---------------- Kernel 2: fused transformer block + scoring (MFMA) ---------
__device__ __forceinline__ void gemm2x2(
    const u16* __restrict__ Alds, const u16* __restrict__ Blds,
    int n0, int nvalid, int fl, int fq, f32x4 acc[2][2])
{
    #pragma unroll
    for (int ks = 0; ks < 4; ++ks) {
        const int kb = ks * 32 + fq * 8;
        bf16x8 a0 = *(const bf16x8*)(Alds + fl * SWB + kb);
        bf16x8 a1 = *(const bf16x8*)(Alds + (16 + fl) * SWB + kb);
        bf16x8 b0 = *(const bf16x8*)(Blds + (n0 + fl) * SWB + kb);
        acc[0][0] = __builtin_amdgcn_mfma_f32_16x16x32_bf16(a0, b0, acc[0][0], 0, 0, 0);
        acc[1][0] = __builtin_amdgcn_mfma_f32_16x16x32_bf16(a1, b0, acc[1][0], 0, 0, 0);
        if (nvalid > 1) {
            bf16x8 b1 = *(const bf16x8*)(Blds + (n0 + 16 + fl) * SWB + kb);
            acc[0][1] = __builtin_amdgcn_mfma_f32_16x16x32_bf16(a0, b1, acc[0][1], 0, 0, 0);
            acc[1][1] = __builtin_amdgcn_mfma_f32_16x16x32_bf16(a1, b1, acc[1][1], 0, 0, 0);
        }
    }
}

template<bool TOBF>
__device__ __forceinline__ void ln_tile(float* __restrict__ A, u16* __restrict__ dstbf,
        const float* __restrict__ g, const float* __restrict__ b, int tid)
{
    const int r  = tid >> 3;
    const int s8 = tid & 7;
    float sum = 0.f, sq = 0.f;
    for (int k = s8; k < D; k += 8) {
        float v = A[r * 104 + k];
        sum += v; sq += v * v;
    }
    sum += __shfl_xor(sum, 1, 64); sq += __shfl_xor(sq, 1, 64);
    sum += __shfl_xor(sum, 2, 64); sq += __shfl_xor(sq, 2, 64);
    sum += __shfl_xor(sum, 4, 64); sq += __shfl_xor(sq, 4, 64);
    float m   = sum * 0.01f;
    float var = sq * 0.01f - m * m;
    float rs  = rsqrtf(var + EPSV);
    for (int k = s8; k < D; k += 8) {
        float v = A[r * 104 + k];
        float y = (v - m) * rs * g[k] + b[k];
        A[r * 104 + k] = y;
        if (TOBF) dstbf[r * SWB + k] = f2bf(y);
    }
}

__global__ __launch_bounds__(256) void k_fused(
    const float* __restrict__ xin,
    const int*  __restrict__ ipred,
    const u16*  __restrict__ wbase,        // prep region
    const float* __restrict__ rec_b,
    const float* __restrict__ bcomb,
    const float* __restrict__ ln1g, const float* __restrict__ ln1b,
    const float* __restrict__ ln2g, const float* __restrict__ ln2b,
    const float* __restrict__ b1, const float* __restrict__ b2,
    float* __restrict__ out)
{
    __shared__ __align__(16) float A0[ROWS * 104];     // x -> x+attn -> h -> h+f2 -> scores
    __shared__ __align__(16) u16   Abf[ROWS * SWB];    // x -> h -> s (bf16, A-operand)
    __shared__ __align__(16) u16   Hbf[ROWS * SWB];    // H chunk (bf16, A-operand)
    __shared__ __align__(16) u16   Wbuf[128 * SWB];    // B-operand weight tile / rec
    __shared__ float sRB[112];                         // rec_b[0..99]

    const int tid  = threadIdx.x;
    const int wv   = tid >> 6;
    const int lane = tid & 63;
    const int fl   = lane & 15;
    const int fq   = lane >> 4;
    const int row0 = blockIdx.x * ROWS;
    const int n0   = wv * 32;
    const int nv7  = (wv < 3) ? 2 : 1;    // 7 N-tiles over 4 waves

    const u16* Wcp = wbase + WCP_OFF;
    const u16* W1p = wbase + W1P_OFF;
    const u16* W2p = wbase + W2P_OFF;
    const u16* recp= wbase + RECP_OFF;

    // stage x (fp32 + bf16 padded), Wcomb tile, rec_b head
    for (int i = tid; i < ROWS * 128; i += 256) {
        int r = i >> 7, k = i & 127;
        float v = (k < D) ? xin[(size_t)(row0 + r) * D + k] : 0.f;
        if (k < D) A0[r * 104 + k] = v;
        Abf[r * SWB + k] = f2bf(v);
    }
    for (int i = tid; i < 112 * 16; i += 256) {
        int r = i >> 4, cb = (i & 15) * 8;
        *(uint4*)(Wbuf + r * SWB + cb) = *(const uint4*)(Wcp + r * 128 + cb);
    }
    if (tid < D) sRB[tid] = rec_b[tid];
    __syncthreads();

    // ---- attn = x @ Wcomb^T + bcomb ; A0 += attn (V,O folded) ----
    {
        f32x4 acc[2][2] = {};
        gemm2x2(Abf, Wbuf, n0, nv7, fl, fq, acc);
        for (int t = 0; t < nv7; ++t) {
            int c = n0 + t * 16 + fl;
            if (c < D) {
                float bc = bcomb[c];
                #pragma unroll
                for (int r = 0; r < 4; ++r) {
                    int m = fq * 4 + r;
                    A0[m * 104 + c]        += acc[0][t][r] + bc;
                    A0[(16 + m) * 104 + c] += acc[1][t][r] + bc;
                }
            }
        }
        __syncthreads();      // A0 writes visible; Abf/Wbuf reads done
    }

    // ---- LN1: h = LN(x+attn) -> A0 (fp32) + Abf (bf16) ----
    ln_tile<true>(A0, Abf, ln1g, ln1b, tid);

    // ---- FFN: 16 chunks of 128 hidden (direct LDS staging, baseline form) ----
    f32x4 facc[2][2] = {};
    for (int ch = 0; ch < NCH; ++ch) {
        __syncthreads();           // prev gemm2 reads done (also LN1 writes visible)
        {
            const u16* src = W1p + (size_t)ch * CH * 128;
            for (int i = tid; i < 128 * 16; i += 256) {
                int r = i >> 4, cb = (i & 15) * 8;
                *(uint4*)(Wbuf + r * SWB + cb) = *(const uint4*)(src + r * 128 + cb);
            }
        }
        __syncthreads();
        // GEMM1: H = relu(h @ W1c^T + b1c)
        f32x4 hacc[2][2] = {};
        gemm2x2(Abf, Wbuf, n0, 2, fl, fq, hacc);
        __syncthreads();           // gemm1 reads done; Wbuf/Hbf free to overwrite
        #pragma unroll
        for (int t = 0; t < 2; ++t) {
            int c = n0 + t * 16 + fl;
            float b1c = b1[ch * CH + c];
            #pragma unroll
            for (int r = 0; r < 4; ++r) {
                int m = fq * 4 + r;
                Hbf[m * SWB + c]        = f2bf(fmaxf(hacc[0][t][r] + b1c, 0.f));
                Hbf[(16 + m) * SWB + c] = f2bf(fmaxf(hacc[1][t][r] + b1c, 0.f));
            }
        }
        {
            const u16* src = W2p + ch * CH;
            for (int i = tid; i < 112 * 16; i += 256) {
                int r = i >> 4, cb = (i & 15) * 8;
                *(uint4*)(Wbuf + r * SWB + cb) = *(const uint4*)(src + (size_t)r * FF + cb);
            }
        }
        __syncthreads();
        // GEMM2: facc += H @ W2c^T
        gemm2x2(Hbf, Wbuf, n0, nv7, fl, fq, facc);
    }

    // ---- A0 = h + f2 + b2 ----
    for (int t = 0; t < nv7; ++t) {
        int c = n0 + t * 16 + fl;
        if (c < D) {
            float b2c = b2[c];
            #pragma unroll
            for (int r = 0; r < 4; ++r) {
                int m = fq * 4 + r;
                A0[m * 104 + c]        += facc[0][t][r] + b2c;
                A0[(16 + m) * 104 + c] += facc[1][t][r] + b2c;
            }
        }
    }
    __syncthreads();          // A0 visible; last gemm2's Wbuf/Hbf reads done

    // ---- LN2 -> s (bf16 into Abf); stage rec_emb tile into Wbuf ----
    ln_tile<true>(A0, Abf, ln2g, ln2b, tid);
    for (int i = tid; i < 112 * 16; i += 256) {
        int r = i >> 4, cb = (i & 15) * 8;
        *(uint4*)(Wbuf + r * SWB + cb) = *(const uint4*)(recp + r * 128 + cb);
    }
    __syncthreads();

    // ---- scoring: scores[b, n] = dot(s[b], rec[n]) via MFMA (all n < 100) ----
    {
        f32x4 acc[2][2] = {};
        gemm2x2(Abf, Wbuf, n0, nv7, fl, fq, acc);
        for (int t = 0; t < nv7; ++t) {
            int c = n0 + t * 16 + fl;
            if (c < D) {
                #pragma unroll
                for (int r = 0; r < 4; ++r) {
                    int m = fq * 4 + r;
                    A0[m * 104 + c]        = acc[0][t][r];
                    A0[(16 + m) * 104 + c] = acc[1][t][r];
                }
            }
        }
        __syncthreads();
    }

    // ---- out[b,k] = rec_b[idx] + scores[b, idx] ----
    for (int o = tid; o < ROWS * KP; o += 256) {
        int r = o / KP, k = o - r * KP;
        int grow = row0 + r;
        int idx  = ipred[(size_t)grow * KP + k];
        out[(size_t)grow * KP + k] = sRB[idx] + A0[r * 104 + idx];
    }
}

extern "C" void kernel_launch(void* const* d_in, const int* in_sizes, int n_in,
                              void* d_out, int out_size, void* d_ws, size_t ws_size,
                              hipStream_t stream)
{
    const int*   item_seq   = (const int*)d_in[0];
    const int*   ipred      = (const int*)d_in[1];
    const float* item_emb   = (const float*)d_in[2];
    const float* rec_emb    = (const float*)d_in[3];
    const float* rec_b      = (const float*)d_in[4];
    const float* in_proj_w  = (const float*)d_in[5];
    const float* in_proj_b  = (const float*)d_in[6];
    const float* out_proj_w = (const float*)d_in[7];
    const float* out_proj_b = (const float*)d_in[8];
    const float* ln1g = (const float*)d_in[9];
    const float* ln1b = (const float*)d_in[10];
    const float* ln2g = (const float*)d_in[11];
    const float* ln2b = (const float*)d_in[12];
    const float* w1   = (const float*)d_in[13];
    const float* b1   = (const float*)d_in[14];
    const float* w2   = (const float*)d_in[15];
    const float* b2   = (const float*)d_in[16];

    float* xws    = (float*)d_ws;
    float* bcombf = xws + (size_t)NB * D;
    u16*   wbase  = (u16*)(bcombf + 128);

    k_prep<<<(PREP_N + 128 + 255) / 256, 256, 0, stream>>>(
        in_proj_w, out_proj_w, in_proj_b, out_proj_b, w1, w2, rec_emb, wbase, bcombf);
    k_gather<<<NB, 256, 0, stream>>>(item_seq, item_emb, xws);
    k_fused<<<NB / ROWS, 256, 0, stream>>>(xws, ipred, wbase, rec_b, bcombf,
        ln1g, ln1b, ln2g, ln2b, b1, b2, (float*)d_out);
}

// Round 3
// 660.428 us; speedup vs baseline: 1.1208x; 1.0161x over previous
//
#include <hip/hip_runtime.h>

#define NB   16384
#define LSEQ 50
#define D    100
#define KP   100
#define FF   2048
#define CH   128
#define NCH  (FF/CH)
#define ROWS 32
#define EPSV 1e-5f
#define SWB  136      // LDS u16 stride for MFMA tiles (68 dwords -> conflict-optimal)

typedef unsigned short u16;
typedef unsigned int   u32;
typedef __attribute__((ext_vector_type(8))) short bf16x8;
typedef __attribute__((ext_vector_type(4))) float f32x4;

// d_ws layout: [0, NB*D) fp32 xws ; 128 fp32 bcomb ; then u16 region:
#define WCP_OFF  0          // Wcomb = Wo@Wv padded [112][128]
#define W1P_OFF  14336      // [2048][128]
#define W2P_OFF  276480     // [112][2048]
#define RECP_OFF 505856     // rec padded [112][128]
#define PREP_N   520192
#define PREP_BLKS 2033      // ceil((PREP_N+128)/256)

__device__ __forceinline__ float bflo(u32 u){ return __uint_as_float(u << 16); }
__device__ __forceinline__ float bfhi(u32 u){ return __uint_as_float(u & 0xffff0000u); }
__device__ __forceinline__ u16 f2bf(float f){
    u32 b = __float_as_uint(f);
    b += 0x7fffu + ((b >> 16) & 1u);   // RNE
    return (u16)(b >> 16);
}

// ------ Kernel 0: fused weight-prep + embedding-gather (independent paths) ---
// Blocks [0, PREP_BLKS): weight prep -> padded bf16 layouts (+ V/O fold).
// Blocks [PREP_BLKS, PREP_BLKS+NB): x[row] = sum_l item_emb[item_seq[row,l]].
__global__ __launch_bounds__(256) void k_pg(
    const int*  __restrict__ seq,  const float* __restrict__ emb,
    float* __restrict__ xout,
    const float* __restrict__ ipw, const float* __restrict__ opw,
    const float* __restrict__ ipb, const float* __restrict__ opb,
    const float* __restrict__ w1,  const float* __restrict__ w2,
    const float* __restrict__ rec, u16* __restrict__ dst,
    float* __restrict__ bcomb)
{
    if (blockIdx.x < PREP_BLKS) {
        // ---------------- prep path ----------------
        int i = blockIdx.x * 256 + threadIdx.x;
        if (i >= PREP_N + 128) return;
        if (i < W1P_OFF) {                       // Wcomb = Wo@Wv padded [112][128]
            int n = i >> 7, k = i & 127;
            float a = 0.f;
            if (n < D && k < D) {
                for (int j = 0; j < D; ++j)
                    a += opw[n * D + j] * ipw[(2 * D + j) * D + k];
            }
            dst[i] = f2bf(a);
        } else if (i < W2P_OFF) {                // W1 padded [2048][128]
            int j = i - W1P_OFF; int r = j >> 7, k = j & 127;
            dst[i] = (k < D) ? f2bf(w1[r * D + k]) : (u16)0;
        } else if (i < RECP_OFF) {               // W2 padded [112][2048]
            int j = i - W2P_OFF; int c = j >> 11, jj = j & 2047;
            dst[i] = (c < D) ? f2bf(w2[c * FF + jj]) : (u16)0;
        } else if (i < PREP_N) {                 // rec padded [112][128]
            int j = i - RECP_OFF; int n = j >> 7, k = j & 127;
            dst[i] = (n < D && k < D) ? f2bf(rec[n * D + k]) : (u16)0;
        } else {                                 // bcomb = Wo@bv + bo (fp32)
            int n = i - PREP_N;
            float a = 0.f;
            if (n < D) {
                a = opb[n];
                for (int j = 0; j < D; ++j)
                    a += opw[n * D + j] * ipb[2 * D + j];
            }
            bcomb[n] = a;
        }
        return;
    }

    // ---------------- gather path (float4: rows are 400 B = 25 x 16 B, aligned) ----
    __shared__ float4 part[10][25];
    const int row = blockIdx.x - PREP_BLKS;
    const int t   = threadIdx.x;
    const int c4  = t % 25;          // float4 column 0..24
    const int lg  = t / 25;          // 0..10 (group 10 = 6 threads idle)
    if (lg < 10) {
        const float4* e4 = (const float4*)emb;
        float4 a; a.x = 0.f; a.y = 0.f; a.z = 0.f; a.w = 0.f;
        #pragma unroll
        for (int u = 0; u < 5; ++u) {
            int idx = seq[row * LSEQ + lg * 5 + u];
            float4 w = e4[(size_t)idx * 25 + c4];
            a.x += w.x; a.y += w.y; a.z += w.z; a.w += w.w;
        }
        part[lg][c4] = a;
    }
    __syncthreads();
    if (t < 25) {
        float4 s = part[0][t];
        #pragma unroll
        for (int g = 1; g < 10; ++g) {
            float4 p = part[g][t];
            s.x += p.x; s.y += p.y; s.z += p.z; s.w += p.w;
        }
        ((float4*)xout)[(size_t)row * 25 + t] = s;
    }
}

// ---------------- Kernel 1: fused transformer block + scoring (MFMA) ---------
__device__ __forceinline__ void gemm2x2(
    const u16* __restrict__ Alds, const u16* __restrict__ Blds,
    int n0, int nvalid, int fl, int fq, f32x4 acc[2][2])
{
    #pragma unroll
    for (int ks = 0; ks < 4; ++ks) {
        const int kb = ks * 32 + fq * 8;
        bf16x8 a0 = *(const bf16x8*)(Alds + fl * SWB + kb);
        bf16x8 a1 = *(const bf16x8*)(Alds + (16 + fl) * SWB + kb);
        bf16x8 b0 = *(const bf16x8*)(Blds + (n0 + fl) * SWB + kb);
        acc[0][0] = __builtin_amdgcn_mfma_f32_16x16x32_bf16(a0, b0, acc[0][0], 0, 0, 0);
        acc[1][0] = __builtin_amdgcn_mfma_f32_16x16x32_bf16(a1, b0, acc[1][0], 0, 0, 0);
        if (nvalid > 1) {
            bf16x8 b1 = *(const bf16x8*)(Blds + (n0 + 16 + fl) * SWB + kb);
            acc[0][1] = __builtin_amdgcn_mfma_f32_16x16x32_bf16(a0, b1, acc[0][1], 0, 0, 0);
            acc[1][1] = __builtin_amdgcn_mfma_f32_16x16x32_bf16(a1, b1, acc[1][1], 0, 0, 0);
        }
    }
}

template<bool TOBF>
__device__ __forceinline__ void ln_tile(float* __restrict__ A, u16* __restrict__ dstbf,
        const float* __restrict__ g, const float* __restrict__ b, int tid)
{
    const int r  = tid >> 3;
    const int s8 = tid & 7;
    float sum = 0.f, sq = 0.f;
    for (int k = s8; k < D; k += 8) {
        float v = A[r * 104 + k];
        sum += v; sq += v * v;
    }
    sum += __shfl_xor(sum, 1, 64); sq += __shfl_xor(sq, 1, 64);
    sum += __shfl_xor(sum, 2, 64); sq += __shfl_xor(sq, 2, 64);
    sum += __shfl_xor(sum, 4, 64); sq += __shfl_xor(sq, 4, 64);
    float m   = sum * 0.01f;
    float var = sq * 0.01f - m * m;
    float rs  = rsqrtf(var + EPSV);
    for (int k = s8; k < D; k += 8) {
        float v = A[r * 104 + k];
        float y = (v - m) * rs * g[k] + b[k];
        A[r * 104 + k] = y;
        if (TOBF) dstbf[r * SWB + k] = f2bf(y);
    }
}

__global__ __launch_bounds__(256) void k_fused(
    const float* __restrict__ xin,
    const int*  __restrict__ ipred,
    const u16*  __restrict__ wbase,        // prep region
    const float* __restrict__ rec_b,
    const float* __restrict__ bcomb,
    const float* __restrict__ ln1g, const float* __restrict__ ln1b,
    const float* __restrict__ ln2g, const float* __restrict__ ln2b,
    const float* __restrict__ b1, const float* __restrict__ b2,
    float* __restrict__ out)
{
    __shared__ __align__(16) float A0[ROWS * 104];     // x -> x+attn -> h -> h+f2 -> scores
    __shared__ __align__(16) u16   Abf[ROWS * SWB];    // x -> h -> s (bf16, A-operand)
    __shared__ __align__(16) u16   Hbf[ROWS * SWB];    // H chunk (bf16, A-operand)
    __shared__ __align__(16) u16   Wbuf[128 * SWB];    // B-operand weight tile / rec
    __shared__ float sRB[112];                         // rec_b[0..99]

    const int tid  = threadIdx.x;
    const int wv   = tid >> 6;
    const int lane = tid & 63;
    const int fl   = lane & 15;
    const int fq   = lane >> 4;
    const int row0 = blockIdx.x * ROWS;
    const int n0   = wv * 32;
    const int nv7  = (wv < 3) ? 2 : 1;    // 7 N-tiles over 4 waves

    const u16* Wcp = wbase + WCP_OFF;
    const u16* W1p = wbase + W1P_OFF;
    const u16* W2p = wbase + W2P_OFF;
    const u16* recp= wbase + RECP_OFF;

    // stage x (fp32 + bf16 padded), Wcomb tile, rec_b head
    for (int i = tid; i < ROWS * 128; i += 256) {
        int r = i >> 7, k = i & 127;
        float v = (k < D) ? xin[(size_t)(row0 + r) * D + k] : 0.f;
        if (k < D) A0[r * 104 + k] = v;
        Abf[r * SWB + k] = f2bf(v);
    }
    for (int i = tid; i < 112 * 16; i += 256) {
        int r = i >> 4, cb = (i & 15) * 8;
        *(uint4*)(Wbuf + r * SWB + cb) = *(const uint4*)(Wcp + r * 128 + cb);
    }
    if (tid < D) sRB[tid] = rec_b[tid];
    __syncthreads();

    // ---- attn = x @ Wcomb^T + bcomb ; A0 += attn (V,O folded) ----
    {
        f32x4 acc[2][2] = {};
        gemm2x2(Abf, Wbuf, n0, nv7, fl, fq, acc);
        for (int t = 0; t < nv7; ++t) {
            int c = n0 + t * 16 + fl;
            if (c < D) {
                float bc = bcomb[c];
                #pragma unroll
                for (int r = 0; r < 4; ++r) {
                    int m = fq * 4 + r;
                    A0[m * 104 + c]        += acc[0][t][r] + bc;
                    A0[(16 + m) * 104 + c] += acc[1][t][r] + bc;
                }
            }
        }
        __syncthreads();      // A0 writes visible; Abf/Wbuf reads done
    }

    // ---- LN1: h = LN(x+attn) -> A0 (fp32) + Abf (bf16) ----
    ln_tile<true>(A0, Abf, ln1g, ln1b, tid);

    // ---- FFN: 16 chunks of 128 hidden (direct LDS staging) ----
    f32x4 facc[2][2] = {};
    for (int ch = 0; ch < NCH; ++ch) {
        __syncthreads();           // prev gemm2 reads done (also LN1 writes visible)
        {
            const u16* src = W1p + (size_t)ch * CH * 128;
            for (int i = tid; i < 128 * 16; i += 256) {
                int r = i >> 4, cb = (i & 15) * 8;
                *(uint4*)(Wbuf + r * SWB + cb) = *(const uint4*)(src + r * 128 + cb);
            }
        }
        __syncthreads();
        // GEMM1: H = relu(h @ W1c^T + b1c)
        f32x4 hacc[2][2] = {};
        gemm2x2(Abf, Wbuf, n0, 2, fl, fq, hacc);
        __syncthreads();           // gemm1 reads done; Wbuf/Hbf free to overwrite
        #pragma unroll
        for (int t = 0; t < 2; ++t) {
            int c = n0 + t * 16 + fl;
            float b1c = b1[ch * CH + c];
            #pragma unroll
            for (int r = 0; r < 4; ++r) {
                int m = fq * 4 + r;
                Hbf[m * SWB + c]        = f2bf(fmaxf(hacc[0][t][r] + b1c, 0.f));
                Hbf[(16 + m) * SWB + c] = f2bf(fmaxf(hacc[1][t][r] + b1c, 0.f));
            }
        }
        {
            const u16* src = W2p + ch * CH;
            for (int i = tid; i < 112 * 16; i += 256) {
                int r = i >> 4, cb = (i & 15) * 8;
                *(uint4*)(Wbuf + r * SWB + cb) = *(const uint4*)(src + (size_t)r * FF + cb);
            }
        }
        __syncthreads();
        // GEMM2: facc += H @ W2c^T
        gemm2x2(Hbf, Wbuf, n0, nv7, fl, fq, facc);
    }

    // ---- A0 = h + f2 + b2 ----
    for (int t = 0; t < nv7; ++t) {
        int c = n0 + t * 16 + fl;
        if (c < D) {
            float b2c = b2[c];
            #pragma unroll
            for (int r = 0; r < 4; ++r) {
                int m = fq * 4 + r;
                A0[m * 104 + c]        += facc[0][t][r] + b2c;
                A0[(16 + m) * 104 + c] += facc[1][t][r] + b2c;
            }
        }
    }
    __syncthreads();          // A0 visible; last gemm2's Wbuf/Hbf reads done

    // ---- LN2 -> s (bf16 into Abf); stage rec_emb tile into Wbuf ----
    ln_tile<true>(A0, Abf, ln2g, ln2b, tid);
    for (int i = tid; i < 112 * 16; i += 256) {
        int r = i >> 4, cb = (i & 15) * 8;
        *(uint4*)(Wbuf + r * SWB + cb) = *(const uint4*)(recp + r * 128 + cb);
    }
    __syncthreads();

    // ---- scoring: scores[b, n] = dot(s[b], rec[n]) via MFMA (all n < 100) ----
    {
        f32x4 acc[2][2] = {};
        gemm2x2(Abf, Wbuf, n0, nv7, fl, fq, acc);
        for (int t = 0; t < nv7; ++t) {
            int c = n0 + t * 16 + fl;
            if (c < D) {
                #pragma unroll
                for (int r = 0; r < 4; ++r) {
                    int m = fq * 4 + r;
                    A0[m * 104 + c]        = acc[0][t][r];
                    A0[(16 + m) * 104 + c] = acc[1][t][r];
                }
            }
        }
        __syncthreads();
    }

    // ---- out[b,k] = rec_b[idx] + scores[b, idx] ----
    for (int o = tid; o < ROWS * KP; o += 256) {
        int r = o / KP, k = o - r * KP;
        int grow = row0 + r;
        int idx  = ipred[(size_t)grow * KP + k];
        out[(size_t)grow * KP + k] = sRB[idx] + A0[r * 104 + idx];
    }
}

extern "C" void kernel_launch(void* const* d_in, const int* in_sizes, int n_in,
                              void* d_out, int out_size, void* d_ws, size_t ws_size,
                              hipStream_t stream)
{
    const int*   item_seq   = (const int*)d_in[0];
    const int*   ipred      = (const int*)d_in[1];
    const float* item_emb   = (const float*)d_in[2];
    const float* rec_emb    = (const float*)d_in[3];
    const float* rec_b      = (const float*)d_in[4];
    const float* in_proj_w  = (const float*)d_in[5];
    const float* in_proj_b  = (const float*)d_in[6];
    const float* out_proj_w = (const float*)d_in[7];
    const float* out_proj_b = (const float*)d_in[8];
    const float* ln1g = (const float*)d_in[9];
    const float* ln1b = (const float*)d_in[10];
    const float* ln2g = (const float*)d_in[11];
    const float* ln2b = (const float*)d_in[12];
    const float* w1   = (const float*)d_in[13];
    const float* b1   = (const float*)d_in[14];
    const float* w2   = (const float*)d_in[15];
    const float* b2   = (const float*)d_in[16];

    float* xws    = (float*)d_ws;
    float* bcombf = xws + (size_t)NB * D;
    u16*   wbase  = (u16*)(bcombf + 128);

    k_pg<<<PREP_BLKS + NB, 256, 0, stream>>>(
        item_seq, item_emb, xws,
        in_proj_w, out_proj_w, in_proj_b, out_proj_b, w1, w2, rec_emb,
        wbase, bcombf);
    k_fused<<<NB / ROWS, 256, 0, stream>>>(xws, ipred, wbase, rec_b, bcombf,
        ln1g, ln1b, ln2g, ln2b, b1, b2, (float*)d_out);
}